// Round 15
// baseline (644.364 us; speedup 1.0000x reference)
//
#include <hip/hip_runtime.h>
#include <math.h>

#define BATCH 2
#define NHEAD 16
#define SEQ   2048
#define HD    64
#define EMB   1024

// Compiler-only memory fence (r7 post-mortem): wave-private LDS phases need
// compile-time ordering only; hardware DS is in-order per wave.
#define LDS_FENCE() asm volatile("" ::: "memory")

// ---------------------------------------------------------------------------
// Eigen-AVX-emulating f32 GEMM for q AND k (DECISION PATH), double-buffered.
// Staging changed ONLY (prefetch + 2 LDS buffers + 1 barrier/tile); the
// per-element FP chain is bit-frozen r9 semantics: 4 k-panels of 256,
// sequential mul-then-add within panel (__fmul_rn/__fadd_rn), panels summed
// in order, + bias. blockIdx.z selects q/k pointers (single code path).
// ---------------------------------------------------------------------------
__global__ __launch_bounds__(256)
void gemm_eigen_qk(const float* __restrict__ x,
                   const float* __restrict__ Wq, const float* __restrict__ bq,
                   const float* __restrict__ Wk, const float* __restrict__ bk,
                   float* __restrict__ qw, float* __restrict__ kw) {
  const int z = blockIdx.z;
  const float* W    = z ? Wk : Wq;
  const float* bias = z ? bk : bq;
  float* out        = z ? kw : qw;

  __shared__ float As[2][16][68];
  __shared__ float Bs[2][16][68];
  const int m0 = blockIdx.x * 64;
  const int n0 = blockIdx.y * 64;
  const int t  = threadIdx.x;
  const int tx = t & 15, ty = t >> 4;
  const int ar = t >> 2, ac = (t & 3) * 4;
  const int br = t >> 4, bc = (t & 15) * 4;

  float tot[4][4] = {};
  float acc[4][4] = {};

  // prologue: stage tile 0 into buffer 0
  {
    float4 av = *(const float4*)&x[(size_t)(m0 + ar) * EMB + ac];
    float4 bv = *(const float4*)&W[(size_t)br * EMB + n0 + bc];
    As[0][ac + 0][ar] = av.x;
    As[0][ac + 1][ar] = av.y;
    As[0][ac + 2][ar] = av.z;
    As[0][ac + 3][ar] = av.w;
    *(float4*)&Bs[0][br][bc] = bv;
  }
  __syncthreads();

  for (int kt = 0; kt < 64; ++kt) {
    const int cur = kt & 1, nxt = cur ^ 1;
    float4 av2, bv2;
    if (kt < 63) {                       // prefetch tile kt+1 (overlaps compute)
      const int k0 = (kt + 1) * 16;
      av2 = *(const float4*)&x[(size_t)(m0 + ar) * EMB + k0 + ac];
      bv2 = *(const float4*)&W[(size_t)(k0 + br) * EMB + n0 + bc];
    }
#pragma unroll
    for (int kk = 0; kk < 16; ++kk) {
      float4 a = *(const float4*)&As[cur][kk][ty * 4];
      float4 b = *(const float4*)&Bs[cur][kk][tx * 4];
      float aa[4] = {a.x, a.y, a.z, a.w};
      float bb[4] = {b.x, b.y, b.z, b.w};
#pragma unroll
      for (int i = 0; i < 4; ++i)
#pragma unroll
        for (int j = 0; j < 4; ++j)
          acc[i][j] = __fadd_rn(acc[i][j], __fmul_rn(aa[i], bb[j]));
    }
    if ((kt & 15) == 15) {               // panel boundary (k multiple of 256)
#pragma unroll
      for (int i = 0; i < 4; ++i)
#pragma unroll
        for (int j = 0; j < 4; ++j) {
          tot[i][j] = __fadd_rn(tot[i][j], acc[i][j]);  // panel sums in order
          acc[i][j] = 0.f;
        }
    }
    if (kt < 63) {
      As[nxt][ac + 0][ar] = av2.x;
      As[nxt][ac + 1][ar] = av2.y;
      As[nxt][ac + 2][ar] = av2.z;
      As[nxt][ac + 3][ar] = av2.w;
      *(float4*)&Bs[nxt][br][bc] = bv2;
    }
    __syncthreads();                     // one barrier per tile
  }

#pragma unroll
  for (int i = 0; i < 4; ++i) {
    const int m = m0 + ty * 4 + i;
#pragma unroll
    for (int j = 0; j < 4; ++j) {
      const int n = n0 + tx * 4 + j;
      const float val = __fadd_rn(tot[i][j], bias[n]);
      const int b = m >> 11, s = m & (SEQ - 1);
      const int h = n >> 6,  d = n & (HD - 1);
      out[((((size_t)b * NHEAD + h) * SEQ) + s) * HD + d] = val;
    }
  }
}

// ---------------------------------------------------------------------------
// FMA f32 GEMM (VALUE PATH — v / out projections), same double-buffered
// staging; fmaf accumulation chain unchanged (value path, precision-free).
// ---------------------------------------------------------------------------
template<int MODE>
__global__ __launch_bounds__(256)
void gemm_fma(const float* __restrict__ A, const float* __restrict__ W,
              const float* __restrict__ bias, float* __restrict__ out) {
  __shared__ float As[2][16][68];
  __shared__ float Bs[2][16][68];
  const int m0 = blockIdx.x * 64;
  const int n0 = blockIdx.y * 64;
  const int t  = threadIdx.x;
  const int tx = t & 15, ty = t >> 4;
  const int ar = t >> 2, ac = (t & 3) * 4;
  const int br = t >> 4, bc = (t & 15) * 4;

  float acc[4][4] = {};

  {
    float4 av = *(const float4*)&A[(size_t)(m0 + ar) * EMB + ac];
    float4 bv = *(const float4*)&W[(size_t)br * EMB + n0 + bc];
    As[0][ac + 0][ar] = av.x;
    As[0][ac + 1][ar] = av.y;
    As[0][ac + 2][ar] = av.z;
    As[0][ac + 3][ar] = av.w;
    *(float4*)&Bs[0][br][bc] = bv;
  }
  __syncthreads();

  for (int kt = 0; kt < 64; ++kt) {
    const int cur = kt & 1, nxt = cur ^ 1;
    float4 av2, bv2;
    if (kt < 63) {
      const int k0 = (kt + 1) * 16;
      av2 = *(const float4*)&A[(size_t)(m0 + ar) * EMB + k0 + ac];
      bv2 = *(const float4*)&W[(size_t)(k0 + br) * EMB + n0 + bc];
    }
#pragma unroll
    for (int kk = 0; kk < 16; ++kk) {
      float4 a = *(const float4*)&As[cur][kk][ty * 4];
      float4 b = *(const float4*)&Bs[cur][kk][tx * 4];
      float aa[4] = {a.x, a.y, a.z, a.w};
      float bb[4] = {b.x, b.y, b.z, b.w};
#pragma unroll
      for (int i = 0; i < 4; ++i)
#pragma unroll
        for (int j = 0; j < 4; ++j)
          acc[i][j] = fmaf(aa[i], bb[j], acc[i][j]);
    }
    if (kt < 63) {
      As[nxt][ac + 0][ar] = av2.x;
      As[nxt][ac + 1][ar] = av2.y;
      As[nxt][ac + 2][ar] = av2.z;
      As[nxt][ac + 3][ar] = av2.w;
      *(float4*)&Bs[nxt][br][bc] = bv2;
    }
    __syncthreads();
  }

#pragma unroll
  for (int i = 0; i < 4; ++i) {
    const int m = m0 + ty * 4 + i;
#pragma unroll
    for (int j = 0; j < 4; ++j) {
      const int n = n0 + tx * 4 + j;
      const float val = acc[i][j] + bias[n];
      if (MODE == 0) {
        out[(size_t)m * EMB + n] = val;
      } else {
        const int b = m >> 11, s = m & (SEQ - 1);
        const int h = n >> 6,  d = n & (HD - 1);
        out[((((size_t)b * NHEAD + h) * SEQ) + s) * HD + d] = val;
      }
    }
  }
}

// ---------------------------------------------------------------------------
// Pruning + sparse attention v8 (r13 verbatim, bit-proven 0.0078125):
// cooperative quad loads for level/final dots, rank-based selection,
// single-buffer idx, LDS-broadcast PV.
// ---------------------------------------------------------------------------
template<int CS>
__device__ __forceinline__ void level8(const float* kb, int qg, int lane,
                                       float (*q_lds)[68], float (*scr)[68],
                                       short (*idx)[256], int (*sel)[8]) {
  const int cq = lane >> 2;   // candidate 0..15
  const int tq = lane & 3;    // quad sub-lane
#pragma unroll
  for (int qq = 0; qq < 4; ++qq) {
    const int qi  = qg + qq;
    const int rep = idx[qi][cq * CS + (CS >> 1)];
    const float* kr = kb + (size_t)rep * HD;
    const float* qr = &q_lds[qi][0];
    float p = 0.f;
#pragma unroll
    for (int u = 0; u < 4; ++u) {
      const int f0 = (u * 4 + tq) * 4;    // interleaved 16B chunks
      const float4 kv = *(const float4*)&kr[f0];
      const float4 qv = *(const float4*)&qr[f0];
      p = fmaf(qv.x, kv.x, p);
      p = fmaf(qv.y, kv.y, p);
      p = fmaf(qv.z, kv.z, p);
      p = fmaf(qv.w, kv.w, p);
    }
    p += __shfl_xor(p, 1);
    p += __shfl_xor(p, 2);              // all 4 lanes hold candidate score
    if (tq == 0) scr[qi][cq] = p;
  }
  LDS_FENCE();

  const int c  = lane & 15;
  const int qi = qg + (lane >> 4);
  const float sv = scr[qi][c];
  int cnt = 0;
#pragma unroll
  for (int g = 0; g < 4; ++g) {
    const float4 vv = *(const float4*)&scr[qi][g * 4];
    cnt += (vv.x > sv) || (vv.x == sv && (g * 4 + 0) < c) ? 1 : 0;
    cnt += (vv.y > sv) || (vv.y == sv && (g * 4 + 1) < c) ? 1 : 0;
    cnt += (vv.z > sv) || (vv.z == sv && (g * 4 + 2) < c) ? 1 : 0;
    cnt += (vv.w > sv) || (vv.w == sv && (g * 4 + 3) < c) ? 1 : 0;
  }
  if (cnt < 8) sel[qi][cnt] = c;        // ranks unique -> exactly 8 writers
  LDS_FENCE();
  const int srcp = sel[qi][c >> 1] * CS + (c & 1) * (CS >> 1);
  const int dstp = c * (CS >> 1);
  if (CS == 16) {
    const uint4 t = *(const uint4*)&idx[qi][srcp];
    LDS_FENCE();
    *(uint4*)&idx[qi][dstp] = t;
  } else if (CS == 8) {
    const uint2 t = *(const uint2*)&idx[qi][srcp];
    LDS_FENCE();
    *(uint2*)&idx[qi][dstp] = t;
  } else if (CS == 4) {
    const unsigned t = *(const unsigned*)&idx[qi][srcp];
    LDS_FENCE();
    *(unsigned*)&idx[qi][dstp] = t;
  } else {
    const short t = idx[qi][srcp];
    LDS_FENCE();
    idx[qi][dstp] = t;
  }
  LDS_FENCE();
}

__global__ __launch_bounds__(256, 8)
void prune_attn8(const float* q, const float* k,
                 const float* v, float* ctx) {
  const int blk  = (blockIdx.x & 7) * 512 + (blockIdx.x >> 3);  // XCD swizzle
  const int tile = blk & 127;
  const int bh   = blk >> 7;
  const int wv   = threadIdx.x >> 6;
  const int lane = threadIdx.x & 63;
  const int qg   = wv * 4;
  const int s0   = tile * 16 + qg;

  const float* kb = k + (size_t)bh * SEQ * HD;
  const float* vb = v + (size_t)bh * SEQ * HD;
  const float* qb = q + ((size_t)bh * SEQ + s0) * HD;

  __shared__ __align__(16) float q_lds[16][68];
  __shared__ __align__(16) float scr[16][68];
  __shared__ __align__(16) short idx[16][256];
  __shared__ __align__(16) int   sel[16][8];
  __shared__ __align__(16) short kfin[16][16];

#pragma unroll
  for (int qq = 0; qq < 4; ++qq)
    q_lds[qg + qq][lane] = qb[(size_t)qq * HD + lane];
  LDS_FENCE();

  // ---- level 0: lane = chunk; 4 query chains, mul+add d-ascending ----
  float sc0[4] = {0.f, 0.f, 0.f, 0.f};
  {
    const float* krep = kb + (size_t)(lane * 32 + 16) * HD;
#pragma unroll 2
    for (int u = 0; u < 16; ++u) {
      const float4 kv = *(const float4*)&krep[u * 4];
#pragma unroll
      for (int qq = 0; qq < 4; ++qq) {
        const float4 qv = *(const float4*)&q_lds[qg + qq][u * 4];
        sc0[qq] = __fadd_rn(sc0[qq], __fmul_rn(qv.x, kv.x));
        sc0[qq] = __fadd_rn(sc0[qq], __fmul_rn(qv.y, kv.y));
        sc0[qq] = __fadd_rn(sc0[qq], __fmul_rn(qv.z, kv.z));
        sc0[qq] = __fadd_rn(sc0[qq], __fmul_rn(qv.w, kv.w));
      }
    }
  }
#pragma unroll
  for (int qq = 0; qq < 4; ++qq)
    scr[qg + qq][lane] = sc0[qq];
  LDS_FENCE();

  // ---- rank-based top-8 of 64 per query; float4 broadcast reads ----
  {
    int cnt[4] = {0, 0, 0, 0};
#pragma unroll 4
    for (int g = 0; g < 16; ++g) {
#pragma unroll
      for (int qq = 0; qq < 4; ++qq) {
        const float4 vv = *(const float4*)&scr[qg + qq][g * 4];
        const float sv = sc0[qq];
        cnt[qq] += (vv.x > sv) || (vv.x == sv && (g * 4 + 0) < lane) ? 1 : 0;
        cnt[qq] += (vv.y > sv) || (vv.y == sv && (g * 4 + 1) < lane) ? 1 : 0;
        cnt[qq] += (vv.z > sv) || (vv.z == sv && (g * 4 + 2) < lane) ? 1 : 0;
        cnt[qq] += (vv.w > sv) || (vv.w == sv && (g * 4 + 3) < lane) ? 1 : 0;
      }
    }
#pragma unroll
    for (int qq = 0; qq < 4; ++qq)
      if (cnt[qq] < 8) sel[qg + qq][cnt[qq]] = lane;
  }
  LDS_FENCE();

  // ---- idx fill: 256 entries/query, 4 per lane, packed 8B writes ----
#pragma unroll
  for (int qq = 0; qq < 4; ++qq) {
    const int p0   = lane * 4;
    const int base = sel[qg + qq][p0 >> 5] * 32 + (p0 & 31);
    uint2 pk;
    pk.x = (unsigned)(base & 0xffff) | ((unsigned)(base + 1) << 16);
    pk.y = (unsigned)((base + 2) & 0xffff) | ((unsigned)(base + 3) << 16);
    *(uint2*)&idx[qg + qq][p0] = pk;
  }
  LDS_FENCE();

  // ---- pruning levels (cooperative quad loads) ----
  level8<16>(kb, qg, lane, q_lds, scr, idx, sel);
  level8< 8>(kb, qg, lane, q_lds, scr, idx, sel);
  level8< 4>(kb, qg, lane, q_lds, scr, idx, sel);
  level8< 2>(kb, qg, lane, q_lds, scr, idx, sel);

  // ---- final: 16 keys, cooperative quad dot, scale 1/8 ----
  {
    const int cq = lane >> 2;
    const int tq = lane & 3;
#pragma unroll
    for (int qq = 0; qq < 4; ++qq) {
      const int qi   = qg + qq;
      const int kidx = idx[qi][cq];
      const float* kr = kb + (size_t)kidx * HD;
      const float* qr = &q_lds[qi][0];
      float p = 0.f;
#pragma unroll
      for (int u = 0; u < 4; ++u) {
        const int f0 = (u * 4 + tq) * 4;
        const float4 kv = *(const float4*)&kr[f0];
        const float4 qv = *(const float4*)&qr[f0];
        p = fmaf(qv.x, kv.x, p);
        p = fmaf(qv.y, kv.y, p);
        p = fmaf(qv.z, kv.z, p);
        p = fmaf(qv.w, kv.w, p);
      }
      p += __shfl_xor(p, 1);
      p += __shfl_xor(p, 2);
      if (tq == 0) scr[qi][cq] = __fmul_rn(p, 0.125f);
    }
  }
  LDS_FENCE();

  // ---- softmax over 16-lane group (butterfly; inputs from LDS) ----
  const int c  = lane & 15;
  const int qi = qg + (lane >> 4);
  const int kidx = idx[qi][c];
  const float sfin = scr[qi][c];
  float mx = sfin;
#pragma unroll
  for (int off = 1; off < 16; off <<= 1) mx = fmaxf(mx, __shfl_xor(mx, off));
  const float e = expf(sfin - mx);
  float sum = e;
#pragma unroll
  for (int off = 1; off < 16; off <<= 1) sum += __shfl_xor(sum, off);
  const float w = __fdiv_rn(e, sum);
  LDS_FENCE();          // all sfin reads retired before w overwrites scr
  scr[qi][c]  = w;
  kfin[qi][c] = (short)kidx;
  LDS_FENCE();

  // ---- PV: lane owns dim d; vector-read w (float4) + kidx (uint4) ----
  const int b = bh >> 4, h = bh & 15;
#pragma unroll
  for (int qq = 0; qq < 4; ++qq) {
    const int qi2 = qg + qq;
    const float4 w0 = *(const float4*)&scr[qi2][0];
    const float4 w1 = *(const float4*)&scr[qi2][4];
    const float4 w2 = *(const float4*)&scr[qi2][8];
    const float4 w3 = *(const float4*)&scr[qi2][12];
    const uint4  kA = *(const uint4*)&kfin[qi2][0];
    const uint4  kB = *(const uint4*)&kfin[qi2][8];
    float acc = 0.f;
    acc = fmaf(w0.x, vb[(size_t)(kA.x & 0xffff) * HD + lane], acc);
    acc = fmaf(w0.y, vb[(size_t)(kA.x >> 16)    * HD + lane], acc);
    acc = fmaf(w0.z, vb[(size_t)(kA.y & 0xffff) * HD + lane], acc);
    acc = fmaf(w0.w, vb[(size_t)(kA.y >> 16)    * HD + lane], acc);
    acc = fmaf(w1.x, vb[(size_t)(kA.z & 0xffff) * HD + lane], acc);
    acc = fmaf(w1.y, vb[(size_t)(kA.z >> 16)    * HD + lane], acc);
    acc = fmaf(w1.z, vb[(size_t)(kA.w & 0xffff) * HD + lane], acc);
    acc = fmaf(w1.w, vb[(size_t)(kA.w >> 16)    * HD + lane], acc);
    acc = fmaf(w2.x, vb[(size_t)(kB.x & 0xffff) * HD + lane], acc);
    acc = fmaf(w2.y, vb[(size_t)(kB.x >> 16)    * HD + lane], acc);
    acc = fmaf(w2.z, vb[(size_t)(kB.y & 0xffff) * HD + lane], acc);
    acc = fmaf(w2.w, vb[(size_t)(kB.y >> 16)    * HD + lane], acc);
    acc = fmaf(w3.x, vb[(size_t)(kB.z & 0xffff) * HD + lane], acc);
    acc = fmaf(w3.y, vb[(size_t)(kB.z >> 16)    * HD + lane], acc);
    acc = fmaf(w3.z, vb[(size_t)(kB.w & 0xffff) * HD + lane], acc);
    acc = fmaf(w3.w, vb[(size_t)(kB.w >> 16)    * HD + lane], acc);
    ctx[((size_t)b * SEQ + (s0 + qq)) * EMB + h * HD + lane] = acc;
  }
}

// ---------------------------------------------------------------------------
extern "C" void kernel_launch(void* const* d_in, const int* in_sizes, int n_in,
                              void* d_out, int out_size, void* d_ws, size_t ws_size,
                              hipStream_t stream) {
  const float* x  = (const float*)d_in[0];
  const float* Wq = (const float*)d_in[1];
  const float* bq = (const float*)d_in[2];
  const float* Wk = (const float*)d_in[3];
  const float* bk = (const float*)d_in[4];
  const float* Wv = (const float*)d_in[5];
  const float* bv = (const float*)d_in[6];
  const float* Wo = (const float*)d_in[7];
  const float* bo = (const float*)d_in[8];
  float* out = (float*)d_out;

  const size_t SZ = (size_t)BATCH * NHEAD * SEQ * HD;
  float* qw = (float*)d_ws;
  float* kw = qw + SZ;
  float* vw = kw + SZ;
  float* cw = vw + SZ;

  dim3 blk(256);
  gemm_eigen_qk<<<dim3(64, 16, 2), blk, 0, stream>>>(x, Wq, bq, Wk, bk, qw, kw);
  gemm_fma<1><<<dim3(64, 16), blk, 0, stream>>>(x, Wv, bv, vw);
  prune_attn8<<<dim3(BATCH * NHEAD * (SEQ / 16)), blk, 0, stream>>>(qw, kw, vw, cw);
  gemm_fma<0><<<dim3(64, 16), blk, 0, stream>>>(cw, Wo, bo, out);
}

// Round 16
// 637.111 us; speedup vs baseline: 1.0114x; 1.0114x over previous
//
#include <hip/hip_runtime.h>
#include <math.h>

#define BATCH 2
#define NHEAD 16
#define SEQ   2048
#define HD    64
#define EMB   1024

// Compiler-only memory fence (r7 post-mortem): wave-private LDS phases need
// compile-time ordering only; hardware DS is in-order per wave.
#define LDS_FENCE() asm volatile("" ::: "memory")

// ---------------------------------------------------------------------------
// Eigen-AVX-emulating f32 GEMM for q AND k (DECISION PATH — bit-frozen body,
// r9 verbatim; blockIdx.z only selects W/bias/out pointers, single code path):
// 4 k-panels of 256, sequential mul-then-add within panel, panels summed in
// order, + bias. Output in head layout. [r13-proven best: 250 us]
// ---------------------------------------------------------------------------
__global__ __launch_bounds__(256)
void gemm_eigen_qk(const float* __restrict__ x,
                   const float* __restrict__ Wq, const float* __restrict__ bq,
                   const float* __restrict__ Wk, const float* __restrict__ bk,
                   float* __restrict__ qw, float* __restrict__ kw) {
  const int z = blockIdx.z;
  const float* W    = z ? Wk : Wq;
  const float* bias = z ? bk : bq;
  float* out        = z ? kw : qw;

  __shared__ float As[16][68];
  __shared__ float Bs[16][68];
  const int m0 = blockIdx.x * 64;
  const int n0 = blockIdx.y * 64;
  const int t  = threadIdx.x;
  const int tx = t & 15, ty = t >> 4;
  const int ar = t >> 2, ac = (t & 3) * 4;
  const int br = t >> 4, bc = (t & 15) * 4;

  float tot[4][4] = {};
  float acc[4][4] = {};

  for (int p = 0; p < 4; ++p) {
    for (int kt = 0; kt < 16; ++kt) {
      const int k0 = p * 256 + kt * 16;
      float4 av = *(const float4*)&x[(size_t)(m0 + ar) * EMB + k0 + ac];
      *(float4*)&Bs[br][bc] = *(const float4*)&W[(size_t)(k0 + br) * EMB + n0 + bc];
      As[ac + 0][ar] = av.x;
      As[ac + 1][ar] = av.y;
      As[ac + 2][ar] = av.z;
      As[ac + 3][ar] = av.w;
      __syncthreads();
#pragma unroll
      for (int kk = 0; kk < 16; ++kk) {
        float4 a = *(const float4*)&As[kk][ty * 4];
        float4 b = *(const float4*)&Bs[kk][tx * 4];
        float aa[4] = {a.x, a.y, a.z, a.w};
        float bb[4] = {b.x, b.y, b.z, b.w};
#pragma unroll
        for (int i = 0; i < 4; ++i)
#pragma unroll
          for (int j = 0; j < 4; ++j)
            acc[i][j] = __fadd_rn(acc[i][j], __fmul_rn(aa[i], bb[j]));
      }
      __syncthreads();
    }
#pragma unroll
    for (int i = 0; i < 4; ++i)
#pragma unroll
      for (int j = 0; j < 4; ++j) {
        tot[i][j] = __fadd_rn(tot[i][j], acc[i][j]);   // panel sums in order
        acc[i][j] = 0.f;
      }
  }

#pragma unroll
  for (int i = 0; i < 4; ++i) {
    const int m = m0 + ty * 4 + i;
#pragma unroll
    for (int j = 0; j < 4; ++j) {
      const int n = n0 + tx * 4 + j;
      const float val = __fadd_rn(tot[i][j], bias[n]);
      const int b = m >> 11, s = m & (SEQ - 1);
      const int h = n >> 6,  d = n & (HD - 1);
      out[((((size_t)b * NHEAD + h) * SEQ) + s) * HD + d] = val;
    }
  }
}

// ---------------------------------------------------------------------------
// FMA f32 GEMM (VALUE PATH — v / out projections; r9 verbatim).
// At the VALU-issue roofline: ~55 us vs 54.7 us floor.
// ---------------------------------------------------------------------------
template<int MODE>
__global__ __launch_bounds__(256)
void gemm_fma(const float* __restrict__ A, const float* __restrict__ W,
              const float* __restrict__ bias, float* __restrict__ out) {
  __shared__ float As[16][68];
  __shared__ float Bs[16][68];
  const int m0 = blockIdx.x * 64;
  const int n0 = blockIdx.y * 64;
  const int t  = threadIdx.x;
  const int tx = t & 15, ty = t >> 4;
  const int ar = t >> 2, ac = (t & 3) * 4;
  const int br = t >> 4, bc = (t & 15) * 4;

  float acc[4][4] = {};

  for (int k0 = 0; k0 < EMB; k0 += 16) {
    float4 av = *(const float4*)&A[(size_t)(m0 + ar) * EMB + k0 + ac];
    *(float4*)&Bs[br][bc] = *(const float4*)&W[(size_t)(k0 + br) * EMB + n0 + bc];
    As[ac + 0][ar] = av.x;
    As[ac + 1][ar] = av.y;
    As[ac + 2][ar] = av.z;
    As[ac + 3][ar] = av.w;
    __syncthreads();
#pragma unroll
    for (int kk = 0; kk < 16; ++kk) {
      float4 a = *(const float4*)&As[kk][ty * 4];
      float4 b = *(const float4*)&Bs[kk][tx * 4];
      float aa[4] = {a.x, a.y, a.z, a.w};
      float bb[4] = {b.x, b.y, b.z, b.w};
#pragma unroll
      for (int i = 0; i < 4; ++i)
#pragma unroll
        for (int j = 0; j < 4; ++j)
          acc[i][j] = fmaf(aa[i], bb[j], acc[i][j]);
    }
    __syncthreads();
  }

#pragma unroll
  for (int i = 0; i < 4; ++i) {
    const int m = m0 + ty * 4 + i;
#pragma unroll
    for (int j = 0; j < 4; ++j) {
      const int n = n0 + tx * 4 + j;
      const float val = acc[i][j] + bias[n];
      if (MODE == 0) {
        out[(size_t)m * EMB + n] = val;
      } else {
        const int b = m >> 11, s = m & (SEQ - 1);
        const int h = n >> 6,  d = n & (HD - 1);
        out[((((size_t)b * NHEAD + h) * SEQ) + s) * HD + d] = val;
      }
    }
  }
}

// ---------------------------------------------------------------------------
// Pruning + sparse attention v8 (r13 verbatim, bit-proven 0.0078125):
// cooperative quad loads for level/final dots, rank-based selection,
// single-buffer idx, LDS-broadcast PV. Latency-bound on the algorithmically
// serial 5-level gather chain; occupancy at the 32-wave/CU cap.
// ---------------------------------------------------------------------------
template<int CS>
__device__ __forceinline__ void level8(const float* kb, int qg, int lane,
                                       float (*q_lds)[68], float (*scr)[68],
                                       short (*idx)[256], int (*sel)[8]) {
  const int cq = lane >> 2;   // candidate 0..15
  const int tq = lane & 3;    // quad sub-lane
#pragma unroll
  for (int qq = 0; qq < 4; ++qq) {
    const int qi  = qg + qq;
    const int rep = idx[qi][cq * CS + (CS >> 1)];
    const float* kr = kb + (size_t)rep * HD;
    const float* qr = &q_lds[qi][0];
    float p = 0.f;
#pragma unroll
    for (int u = 0; u < 4; ++u) {
      const int f0 = (u * 4 + tq) * 4;    // interleaved 16B chunks
      const float4 kv = *(const float4*)&kr[f0];
      const float4 qv = *(const float4*)&qr[f0];
      p = fmaf(qv.x, kv.x, p);
      p = fmaf(qv.y, kv.y, p);
      p = fmaf(qv.z, kv.z, p);
      p = fmaf(qv.w, kv.w, p);
    }
    p += __shfl_xor(p, 1);
    p += __shfl_xor(p, 2);              // all 4 lanes hold candidate score
    if (tq == 0) scr[qi][cq] = p;
  }
  LDS_FENCE();

  const int c  = lane & 15;
  const int qi = qg + (lane >> 4);
  const float sv = scr[qi][c];
  int cnt = 0;
#pragma unroll
  for (int g = 0; g < 4; ++g) {
    const float4 vv = *(const float4*)&scr[qi][g * 4];
    cnt += (vv.x > sv) || (vv.x == sv && (g * 4 + 0) < c) ? 1 : 0;
    cnt += (vv.y > sv) || (vv.y == sv && (g * 4 + 1) < c) ? 1 : 0;
    cnt += (vv.z > sv) || (vv.z == sv && (g * 4 + 2) < c) ? 1 : 0;
    cnt += (vv.w > sv) || (vv.w == sv && (g * 4 + 3) < c) ? 1 : 0;
  }
  if (cnt < 8) sel[qi][cnt] = c;        // ranks unique -> exactly 8 writers
  LDS_FENCE();
  const int srcp = sel[qi][c >> 1] * CS + (c & 1) * (CS >> 1);
  const int dstp = c * (CS >> 1);
  if (CS == 16) {
    const uint4 t = *(const uint4*)&idx[qi][srcp];
    LDS_FENCE();
    *(uint4*)&idx[qi][dstp] = t;
  } else if (CS == 8) {
    const uint2 t = *(const uint2*)&idx[qi][srcp];
    LDS_FENCE();
    *(uint2*)&idx[qi][dstp] = t;
  } else if (CS == 4) {
    const unsigned t = *(const unsigned*)&idx[qi][srcp];
    LDS_FENCE();
    *(unsigned*)&idx[qi][dstp] = t;
  } else {
    const short t = idx[qi][srcp];
    LDS_FENCE();
    idx[qi][dstp] = t;
  }
  LDS_FENCE();
}

__global__ __launch_bounds__(256, 8)
void prune_attn8(const float* q, const float* k,
                 const float* v, float* ctx) {
  const int blk  = (blockIdx.x & 7) * 512 + (blockIdx.x >> 3);  // XCD swizzle
  const int tile = blk & 127;
  const int bh   = blk >> 7;
  const int wv   = threadIdx.x >> 6;
  const int lane = threadIdx.x & 63;
  const int qg   = wv * 4;
  const int s0   = tile * 16 + qg;

  const float* kb = k + (size_t)bh * SEQ * HD;
  const float* vb = v + (size_t)bh * SEQ * HD;
  const float* qb = q + ((size_t)bh * SEQ + s0) * HD;

  __shared__ __align__(16) float q_lds[16][68];
  __shared__ __align__(16) float scr[16][68];
  __shared__ __align__(16) short idx[16][256];
  __shared__ __align__(16) int   sel[16][8];
  __shared__ __align__(16) short kfin[16][16];

#pragma unroll
  for (int qq = 0; qq < 4; ++qq)
    q_lds[qg + qq][lane] = qb[(size_t)qq * HD + lane];
  LDS_FENCE();

  // ---- level 0: lane = chunk; 4 query chains, mul+add d-ascending ----
  float sc0[4] = {0.f, 0.f, 0.f, 0.f};
  {
    const float* krep = kb + (size_t)(lane * 32 + 16) * HD;
#pragma unroll 2
    for (int u = 0; u < 16; ++u) {
      const float4 kv = *(const float4*)&krep[u * 4];
#pragma unroll
      for (int qq = 0; qq < 4; ++qq) {
        const float4 qv = *(const float4*)&q_lds[qg + qq][u * 4];
        sc0[qq] = __fadd_rn(sc0[qq], __fmul_rn(qv.x, kv.x));
        sc0[qq] = __fadd_rn(sc0[qq], __fmul_rn(qv.y, kv.y));
        sc0[qq] = __fadd_rn(sc0[qq], __fmul_rn(qv.z, kv.z));
        sc0[qq] = __fadd_rn(sc0[qq], __fmul_rn(qv.w, kv.w));
      }
    }
  }
#pragma unroll
  for (int qq = 0; qq < 4; ++qq)
    scr[qg + qq][lane] = sc0[qq];
  LDS_FENCE();

  // ---- rank-based top-8 of 64 per query; float4 broadcast reads ----
  {
    int cnt[4] = {0, 0, 0, 0};
#pragma unroll 4
    for (int g = 0; g < 16; ++g) {
#pragma unroll
      for (int qq = 0; qq < 4; ++qq) {
        const float4 vv = *(const float4*)&scr[qg + qq][g * 4];
        const float sv = sc0[qq];
        cnt[qq] += (vv.x > sv) || (vv.x == sv && (g * 4 + 0) < lane) ? 1 : 0;
        cnt[qq] += (vv.y > sv) || (vv.y == sv && (g * 4 + 1) < lane) ? 1 : 0;
        cnt[qq] += (vv.z > sv) || (vv.z == sv && (g * 4 + 2) < lane) ? 1 : 0;
        cnt[qq] += (vv.w > sv) || (vv.w == sv && (g * 4 + 3) < lane) ? 1 : 0;
      }
    }
#pragma unroll
    for (int qq = 0; qq < 4; ++qq)
      if (cnt[qq] < 8) sel[qg + qq][cnt[qq]] = lane;
  }
  LDS_FENCE();

  // ---- idx fill: 256 entries/query, 4 per lane, packed 8B writes ----
#pragma unroll
  for (int qq = 0; qq < 4; ++qq) {
    const int p0   = lane * 4;
    const int base = sel[qg + qq][p0 >> 5] * 32 + (p0 & 31);
    uint2 pk;
    pk.x = (unsigned)(base & 0xffff) | ((unsigned)(base + 1) << 16);
    pk.y = (unsigned)((base + 2) & 0xffff) | ((unsigned)(base + 3) << 16);
    *(uint2*)&idx[qg + qq][p0] = pk;
  }
  LDS_FENCE();

  // ---- pruning levels (cooperative quad loads) ----
  level8<16>(kb, qg, lane, q_lds, scr, idx, sel);
  level8< 8>(kb, qg, lane, q_lds, scr, idx, sel);
  level8< 4>(kb, qg, lane, q_lds, scr, idx, sel);
  level8< 2>(kb, qg, lane, q_lds, scr, idx, sel);

  // ---- final: 16 keys, cooperative quad dot, scale 1/8 ----
  {
    const int cq = lane >> 2;
    const int tq = lane & 3;
#pragma unroll
    for (int qq = 0; qq < 4; ++qq) {
      const int qi   = qg + qq;
      const int kidx = idx[qi][cq];
      const float* kr = kb + (size_t)kidx * HD;
      const float* qr = &q_lds[qi][0];
      float p = 0.f;
#pragma unroll
      for (int u = 0; u < 4; ++u) {
        const int f0 = (u * 4 + tq) * 4;
        const float4 kv = *(const float4*)&kr[f0];
        const float4 qv = *(const float4*)&qr[f0];
        p = fmaf(qv.x, kv.x, p);
        p = fmaf(qv.y, kv.y, p);
        p = fmaf(qv.z, kv.z, p);
        p = fmaf(qv.w, kv.w, p);
      }
      p += __shfl_xor(p, 1);
      p += __shfl_xor(p, 2);
      if (tq == 0) scr[qi][cq] = __fmul_rn(p, 0.125f);
    }
  }
  LDS_FENCE();

  // ---- softmax over 16-lane group (butterfly; inputs from LDS) ----
  const int c  = lane & 15;
  const int qi = qg + (lane >> 4);
  const int kidx = idx[qi][c];
  const float sfin = scr[qi][c];
  float mx = sfin;
#pragma unroll
  for (int off = 1; off < 16; off <<= 1) mx = fmaxf(mx, __shfl_xor(mx, off));
  const float e = expf(sfin - mx);
  float sum = e;
#pragma unroll
  for (int off = 1; off < 16; off <<= 1) sum += __shfl_xor(sum, off);
  const float w = __fdiv_rn(e, sum);
  LDS_FENCE();          // all sfin reads retired before w overwrites scr
  scr[qi][c]  = w;
  kfin[qi][c] = (short)kidx;
  LDS_FENCE();

  // ---- PV: lane owns dim d; vector-read w (float4) + kidx (uint4) ----
  const int b = bh >> 4, h = bh & 15;
#pragma unroll
  for (int qq = 0; qq < 4; ++qq) {
    const int qi2 = qg + qq;
    const float4 w0 = *(const float4*)&scr[qi2][0];
    const float4 w1 = *(const float4*)&scr[qi2][4];
    const float4 w2 = *(const float4*)&scr[qi2][8];
    const float4 w3 = *(const float4*)&scr[qi2][12];
    const uint4  kA = *(const uint4*)&kfin[qi2][0];
    const uint4  kB = *(const uint4*)&kfin[qi2][8];
    float acc = 0.f;
    acc = fmaf(w0.x, vb[(size_t)(kA.x & 0xffff) * HD + lane], acc);
    acc = fmaf(w0.y, vb[(size_t)(kA.x >> 16)    * HD + lane], acc);
    acc = fmaf(w0.z, vb[(size_t)(kA.y & 0xffff) * HD + lane], acc);
    acc = fmaf(w0.w, vb[(size_t)(kA.y >> 16)    * HD + lane], acc);
    acc = fmaf(w1.x, vb[(size_t)(kA.z & 0xffff) * HD + lane], acc);
    acc = fmaf(w1.y, vb[(size_t)(kA.z >> 16)    * HD + lane], acc);
    acc = fmaf(w1.z, vb[(size_t)(kA.w & 0xffff) * HD + lane], acc);
    acc = fmaf(w1.w, vb[(size_t)(kA.w >> 16)    * HD + lane], acc);
    acc = fmaf(w2.x, vb[(size_t)(kB.x & 0xffff) * HD + lane], acc);
    acc = fmaf(w2.y, vb[(size_t)(kB.x >> 16)    * HD + lane], acc);
    acc = fmaf(w2.z, vb[(size_t)(kB.y & 0xffff) * HD + lane], acc);
    acc = fmaf(w2.w, vb[(size_t)(kB.y >> 16)    * HD + lane], acc);
    acc = fmaf(w3.x, vb[(size_t)(kB.z & 0xffff) * HD + lane], acc);
    acc = fmaf(w3.y, vb[(size_t)(kB.z >> 16)    * HD + lane], acc);
    acc = fmaf(w3.z, vb[(size_t)(kB.w & 0xffff) * HD + lane], acc);
    acc = fmaf(w3.w, vb[(size_t)(kB.w >> 16)    * HD + lane], acc);
    ctx[((size_t)b * SEQ + (s0 + qq)) * EMB + h * HD + lane] = acc;
  }
}

// ---------------------------------------------------------------------------
extern "C" void kernel_launch(void* const* d_in, const int* in_sizes, int n_in,
                              void* d_out, int out_size, void* d_ws, size_t ws_size,
                              hipStream_t stream) {
  const float* x  = (const float*)d_in[0];
  const float* Wq = (const float*)d_in[1];
  const float* bq = (const float*)d_in[2];
  const float* Wk = (const float*)d_in[3];
  const float* bk = (const float*)d_in[4];
  const float* Wv = (const float*)d_in[5];
  const float* bv = (const float*)d_in[6];
  const float* Wo = (const float*)d_in[7];
  const float* bo = (const float*)d_in[8];
  float* out = (float*)d_out;

  const size_t SZ = (size_t)BATCH * NHEAD * SEQ * HD;
  float* qw = (float*)d_ws;
  float* kw = qw + SZ;
  float* vw = kw + SZ;
  float* cw = vw + SZ;

  dim3 blk(256);
  gemm_eigen_qk<<<dim3(64, 16, 2), blk, 0, stream>>>(x, Wq, bq, Wk, bk, qw, kw);
  gemm_fma<1><<<dim3(64, 16), blk, 0, stream>>>(x, Wv, bv, vw);
  prune_attn8<<<dim3(BATCH * NHEAD * (SEQ / 16)), blk, 0, stream>>>(qw, kw, vw, cw);
  gemm_fma<0><<<dim3(64, 16), blk, 0, stream>>>(cw, Wo, bo, out);
}

// Round 17
// 469.533 us; speedup vs baseline: 1.3724x; 1.3569x over previous
//
#include <hip/hip_runtime.h>
#include <math.h>

#define BATCH 2
#define NHEAD 16
#define SEQ   2048
#define HD    64
#define EMB   1024

// Compiler-only memory fence (r7 post-mortem): wave-private LDS phases need
// compile-time ordering only; hardware DS is in-order per wave.
#define LDS_FENCE() asm volatile("" ::: "memory")

typedef short bf16x8 __attribute__((ext_vector_type(8)));
typedef float f32x4  __attribute__((ext_vector_type(4)));

// f32 -> bf16 round-to-nearest-even (finite inputs)
__device__ __forceinline__ unsigned short f2bf(float f) {
  unsigned u = __float_as_uint(f);
  return (unsigned short)((u + 0x7fffu + ((u >> 16) & 1u)) >> 16);
}

// ---------------------------------------------------------------------------
// Eigen-AVX-emulating f32 GEMM for q AND k (DECISION PATH — bit-frozen body,
// r9 verbatim; blockIdx.z selects W/bias/out pointers, single code path):
// 4 k-panels of 256, sequential mul-then-add within panel, panels summed in
// order, + bias. Output in head layout. [best measured: 246 us]
// ---------------------------------------------------------------------------
__global__ __launch_bounds__(256)
void gemm_eigen_qk(const float* __restrict__ x,
                   const float* __restrict__ Wq, const float* __restrict__ bq,
                   const float* __restrict__ Wk, const float* __restrict__ bk,
                   float* __restrict__ qw, float* __restrict__ kw) {
  const int z = blockIdx.z;
  const float* W    = z ? Wk : Wq;
  const float* bias = z ? bk : bq;
  float* out        = z ? kw : qw;

  __shared__ float As[16][68];
  __shared__ float Bs[16][68];
  const int m0 = blockIdx.x * 64;
  const int n0 = blockIdx.y * 64;
  const int t  = threadIdx.x;
  const int tx = t & 15, ty = t >> 4;
  const int ar = t >> 2, ac = (t & 3) * 4;
  const int br = t >> 4, bc = (t & 15) * 4;

  float tot[4][4] = {};
  float acc[4][4] = {};

  for (int p = 0; p < 4; ++p) {
    for (int kt = 0; kt < 16; ++kt) {
      const int k0 = p * 256 + kt * 16;
      float4 av = *(const float4*)&x[(size_t)(m0 + ar) * EMB + k0 + ac];
      *(float4*)&Bs[br][bc] = *(const float4*)&W[(size_t)(k0 + br) * EMB + n0 + bc];
      As[ac + 0][ar] = av.x;
      As[ac + 1][ar] = av.y;
      As[ac + 2][ar] = av.z;
      As[ac + 3][ar] = av.w;
      __syncthreads();
#pragma unroll
      for (int kk = 0; kk < 16; ++kk) {
        float4 a = *(const float4*)&As[kk][ty * 4];
        float4 b = *(const float4*)&Bs[kk][tx * 4];
        float aa[4] = {a.x, a.y, a.z, a.w};
        float bb[4] = {b.x, b.y, b.z, b.w};
#pragma unroll
        for (int i = 0; i < 4; ++i)
#pragma unroll
          for (int j = 0; j < 4; ++j)
            acc[i][j] = __fadd_rn(acc[i][j], __fmul_rn(aa[i], bb[j]));
      }
      __syncthreads();
    }
#pragma unroll
    for (int i = 0; i < 4; ++i)
#pragma unroll
      for (int j = 0; j < 4; ++j) {
        tot[i][j] = __fadd_rn(tot[i][j], acc[i][j]);   // panel sums in order
        acc[i][j] = 0.f;
      }
  }

#pragma unroll
  for (int i = 0; i < 4; ++i) {
    const int m = m0 + ty * 4 + i;
#pragma unroll
    for (int j = 0; j < 4; ++j) {
      const int n = n0 + tx * 4 + j;
      const float val = __fadd_rn(tot[i][j], bias[n]);
      const int b = m >> 11, s = m & (SEQ - 1);
      const int h = n >> 6,  d = n & (HD - 1);
      out[((((size_t)b * NHEAD + h) * SEQ) + s) * HD + d] = val;
    }
  }
}

// ---------------------------------------------------------------------------
// bf16-MFMA GEMM (VALUE PATH — v / out projections; precision-free path).
// 64x64 block tile, 4 waves (wave w -> rows w*16..+15 x all 64 cols),
// K-slab 64, mfma_f32_16x16x32_bf16, f32 accumulate, f32 bias epilogue.
// A and Bt staged in identical [rows][K] bf16 layout (stride 72 -> 2-way
// bank conflict = free); each fragment is one 16B ds_read_b128. Any error
// in the assumed k->(lane>>4,reg) mapping cancels (same permutation for A
// and B); C/D mapping col=lane&15,row=(lane>>4)*4+reg is HW-verified.
// ---------------------------------------------------------------------------
template<int MODE>
__global__ __launch_bounds__(256)
void gemm_mfma(const float* __restrict__ A, const float* __restrict__ W,
               const float* __restrict__ bias, float* __restrict__ out) {
  __shared__ __align__(16) unsigned short As[64][72];   // [m][k] bf16
  __shared__ __align__(16) unsigned short Bt[64][72];   // [n][k] bf16
  const int t  = threadIdx.x;
  const int wv = t >> 6;
  const int l  = t & 63;
  const int m0 = blockIdx.x * 64;
  const int n0 = blockIdx.y * 64;
  const int sr = t >> 2;        // staging row 0..63
  const int sq = t & 3;         // staging quad 0..3

  const int row16 = l & 15;
  const int kg    = l >> 4;

  f32x4 acc[4] = {};

  for (int k0 = 0; k0 < EMB; k0 += 64) {
    // ---- stage A slab: As[m][k] = bf16(A[m0+m][k0+k]) ----
#pragma unroll
    for (int j = 0; j < 4; ++j) {
      const int kc = sq * 16 + j * 4;
      float4 v = *(const float4*)&A[(size_t)(m0 + sr) * EMB + k0 + kc];
      unsigned short p[4] = {f2bf(v.x), f2bf(v.y), f2bf(v.z), f2bf(v.w)};
      *(uint2*)&As[sr][kc] = *(uint2*)p;
    }
    // ---- stage Bt slab: Bt[n][k] = bf16(W[k0+k][n0+n]) ----
#pragma unroll
    for (int j = 0; j < 4; ++j) {
      const int nc = sq * 16 + j * 4;
      float4 v = *(const float4*)&W[(size_t)(k0 + sr) * EMB + n0 + nc];
      Bt[nc + 0][sr] = f2bf(v.x);
      Bt[nc + 1][sr] = f2bf(v.y);
      Bt[nc + 2][sr] = f2bf(v.z);
      Bt[nc + 3][sr] = f2bf(v.w);
    }
    __syncthreads();

    // ---- 2 K-halves x 4 N-tiles of MFMA ----
#pragma unroll
    for (int h = 0; h < 2; ++h) {
      const int kc = h * 32 + kg * 8;
      const bf16x8 af = *(const bf16x8*)&As[wv * 16 + row16][kc];
#pragma unroll
      for (int nt = 0; nt < 4; ++nt) {
        const bf16x8 bf = *(const bf16x8*)&Bt[nt * 16 + row16][kc];
        acc[nt] = __builtin_amdgcn_mfma_f32_16x16x32_bf16(af, bf, acc[nt], 0, 0, 0);
      }
    }
    __syncthreads();
  }

  // ---- epilogue: C[m0+wv*16+kg*4+r][n0+nt*16+row16] = acc[nt][r] + bias ----
#pragma unroll
  for (int nt = 0; nt < 4; ++nt) {
    const int n  = n0 + nt * 16 + row16;
    const float bn = bias[n];
#pragma unroll
    for (int r = 0; r < 4; ++r) {
      const int m = m0 + wv * 16 + kg * 4 + r;
      const float val = acc[nt][r] + bn;
      if (MODE == 0) {
        out[(size_t)m * EMB + n] = val;
      } else {
        const int b = m >> 11, s = m & (SEQ - 1);
        const int h2 = n >> 6, d = n & (HD - 1);
        out[((((size_t)b * NHEAD + h2) * SEQ) + s) * HD + d] = val;
      }
    }
  }
}

// ---------------------------------------------------------------------------
// Pruning + sparse attention v8 (r13 verbatim, bit-proven 0.0078125 decision
// path): cooperative quad loads for level/final dots, rank-based selection,
// single-buffer idx, LDS-broadcast PV. Latency-bound on the algorithmically
// serial 5-level gather chain; occupancy at the 32-wave/CU cap.
// ---------------------------------------------------------------------------
template<int CS>
__device__ __forceinline__ void level8(const float* kb, int qg, int lane,
                                       float (*q_lds)[68], float (*scr)[68],
                                       short (*idx)[256], int (*sel)[8]) {
  const int cq = lane >> 2;   // candidate 0..15
  const int tq = lane & 3;    // quad sub-lane
#pragma unroll
  for (int qq = 0; qq < 4; ++qq) {
    const int qi  = qg + qq;
    const int rep = idx[qi][cq * CS + (CS >> 1)];
    const float* kr = kb + (size_t)rep * HD;
    const float* qr = &q_lds[qi][0];
    float p = 0.f;
#pragma unroll
    for (int u = 0; u < 4; ++u) {
      const int f0 = (u * 4 + tq) * 4;    // interleaved 16B chunks
      const float4 kv = *(const float4*)&kr[f0];
      const float4 qv = *(const float4*)&qr[f0];
      p = fmaf(qv.x, kv.x, p);
      p = fmaf(qv.y, kv.y, p);
      p = fmaf(qv.z, kv.z, p);
      p = fmaf(qv.w, kv.w, p);
    }
    p += __shfl_xor(p, 1);
    p += __shfl_xor(p, 2);              // all 4 lanes hold candidate score
    if (tq == 0) scr[qi][cq] = p;
  }
  LDS_FENCE();

  const int c  = lane & 15;
  const int qi = qg + (lane >> 4);
  const float sv = scr[qi][c];
  int cnt = 0;
#pragma unroll
  for (int g = 0; g < 4; ++g) {
    const float4 vv = *(const float4*)&scr[qi][g * 4];
    cnt += (vv.x > sv) || (vv.x == sv && (g * 4 + 0) < c) ? 1 : 0;
    cnt += (vv.y > sv) || (vv.y == sv && (g * 4 + 1) < c) ? 1 : 0;
    cnt += (vv.z > sv) || (vv.z == sv && (g * 4 + 2) < c) ? 1 : 0;
    cnt += (vv.w > sv) || (vv.w == sv && (g * 4 + 3) < c) ? 1 : 0;
  }
  if (cnt < 8) sel[qi][cnt] = c;        // ranks unique -> exactly 8 writers
  LDS_FENCE();
  const int srcp = sel[qi][c >> 1] * CS + (c & 1) * (CS >> 1);
  const int dstp = c * (CS >> 1);
  if (CS == 16) {
    const uint4 t = *(const uint4*)&idx[qi][srcp];
    LDS_FENCE();
    *(uint4*)&idx[qi][dstp] = t;
  } else if (CS == 8) {
    const uint2 t = *(const uint2*)&idx[qi][srcp];
    LDS_FENCE();
    *(uint2*)&idx[qi][dstp] = t;
  } else if (CS == 4) {
    const unsigned t = *(const unsigned*)&idx[qi][srcp];
    LDS_FENCE();
    *(unsigned*)&idx[qi][dstp] = t;
  } else {
    const short t = idx[qi][srcp];
    LDS_FENCE();
    idx[qi][dstp] = t;
  }
  LDS_FENCE();
}

__global__ __launch_bounds__(256, 8)
void prune_attn8(const float* q, const float* k,
                 const float* v, float* ctx) {
  const int blk  = (blockIdx.x & 7) * 512 + (blockIdx.x >> 3);  // XCD swizzle
  const int tile = blk & 127;
  const int bh   = blk >> 7;
  const int wv   = threadIdx.x >> 6;
  const int lane = threadIdx.x & 63;
  const int qg   = wv * 4;
  const int s0   = tile * 16 + qg;

  const float* kb = k + (size_t)bh * SEQ * HD;
  const float* vb = v + (size_t)bh * SEQ * HD;
  const float* qb = q + ((size_t)bh * SEQ + s0) * HD;

  __shared__ __align__(16) float q_lds[16][68];
  __shared__ __align__(16) float scr[16][68];
  __shared__ __align__(16) short idx[16][256];
  __shared__ __align__(16) int   sel[16][8];
  __shared__ __align__(16) short kfin[16][16];

#pragma unroll
  for (int qq = 0; qq < 4; ++qq)
    q_lds[qg + qq][lane] = qb[(size_t)qq * HD + lane];
  LDS_FENCE();

  // ---- level 0: lane = chunk; 4 query chains, mul+add d-ascending ----
  float sc0[4] = {0.f, 0.f, 0.f, 0.f};
  {
    const float* krep = kb + (size_t)(lane * 32 + 16) * HD;
#pragma unroll 2
    for (int u = 0; u < 16; ++u) {
      const float4 kv = *(const float4*)&krep[u * 4];
#pragma unroll
      for (int qq = 0; qq < 4; ++qq) {
        const float4 qv = *(const float4*)&q_lds[qg + qq][u * 4];
        sc0[qq] = __fadd_rn(sc0[qq], __fmul_rn(qv.x, kv.x));
        sc0[qq] = __fadd_rn(sc0[qq], __fmul_rn(qv.y, kv.y));
        sc0[qq] = __fadd_rn(sc0[qq], __fmul_rn(qv.z, kv.z));
        sc0[qq] = __fadd_rn(sc0[qq], __fmul_rn(qv.w, kv.w));
      }
    }
  }
#pragma unroll
  for (int qq = 0; qq < 4; ++qq)
    scr[qg + qq][lane] = sc0[qq];
  LDS_FENCE();

  // ---- rank-based top-8 of 64 per query; float4 broadcast reads ----
  {
    int cnt[4] = {0, 0, 0, 0};
#pragma unroll 4
    for (int g = 0; g < 16; ++g) {
#pragma unroll
      for (int qq = 0; qq < 4; ++qq) {
        const float4 vv = *(const float4*)&scr[qg + qq][g * 4];
        const float sv = sc0[qq];
        cnt[qq] += (vv.x > sv) || (vv.x == sv && (g * 4 + 0) < lane) ? 1 : 0;
        cnt[qq] += (vv.y > sv) || (vv.y == sv && (g * 4 + 1) < lane) ? 1 : 0;
        cnt[qq] += (vv.z > sv) || (vv.z == sv && (g * 4 + 2) < lane) ? 1 : 0;
        cnt[qq] += (vv.w > sv) || (vv.w == sv && (g * 4 + 3) < lane) ? 1 : 0;
      }
    }
#pragma unroll
    for (int qq = 0; qq < 4; ++qq)
      if (cnt[qq] < 8) sel[qg + qq][cnt[qq]] = lane;
  }
  LDS_FENCE();

  // ---- idx fill: 256 entries/query, 4 per lane, packed 8B writes ----
#pragma unroll
  for (int qq = 0; qq < 4; ++qq) {
    const int p0   = lane * 4;
    const int base = sel[qg + qq][p0 >> 5] * 32 + (p0 & 31);
    uint2 pk;
    pk.x = (unsigned)(base & 0xffff) | ((unsigned)(base + 1) << 16);
    pk.y = (unsigned)((base + 2) & 0xffff) | ((unsigned)(base + 3) << 16);
    *(uint2*)&idx[qg + qq][p0] = pk;
  }
  LDS_FENCE();

  // ---- pruning levels (cooperative quad loads) ----
  level8<16>(kb, qg, lane, q_lds, scr, idx, sel);
  level8< 8>(kb, qg, lane, q_lds, scr, idx, sel);
  level8< 4>(kb, qg, lane, q_lds, scr, idx, sel);
  level8< 2>(kb, qg, lane, q_lds, scr, idx, sel);

  // ---- final: 16 keys, cooperative quad dot, scale 1/8 ----
  {
    const int cq = lane >> 2;
    const int tq = lane & 3;
#pragma unroll
    for (int qq = 0; qq < 4; ++qq) {
      const int qi   = qg + qq;
      const int kidx = idx[qi][cq];
      const float* kr = kb + (size_t)kidx * HD;
      const float* qr = &q_lds[qi][0];
      float p = 0.f;
#pragma unroll
      for (int u = 0; u < 4; ++u) {
        const int f0 = (u * 4 + tq) * 4;
        const float4 kv = *(const float4*)&kr[f0];
        const float4 qv = *(const float4*)&qr[f0];
        p = fmaf(qv.x, kv.x, p);
        p = fmaf(qv.y, kv.y, p);
        p = fmaf(qv.z, kv.z, p);
        p = fmaf(qv.w, kv.w, p);
      }
      p += __shfl_xor(p, 1);
      p += __shfl_xor(p, 2);
      if (tq == 0) scr[qi][cq] = __fmul_rn(p, 0.125f);
    }
  }
  LDS_FENCE();

  // ---- softmax over 16-lane group (butterfly; inputs from LDS) ----
  const int c  = lane & 15;
  const int qi = qg + (lane >> 4);
  const int kidx = idx[qi][c];
  const float sfin = scr[qi][c];
  float mx = sfin;
#pragma unroll
  for (int off = 1; off < 16; off <<= 1) mx = fmaxf(mx, __shfl_xor(mx, off));
  const float e = expf(sfin - mx);
  float sum = e;
#pragma unroll
  for (int off = 1; off < 16; off <<= 1) sum += __shfl_xor(sum, off);
  const float w = __fdiv_rn(e, sum);
  LDS_FENCE();          // all sfin reads retired before w overwrites scr
  scr[qi][c]  = w;
  kfin[qi][c] = (short)kidx;
  LDS_FENCE();

  // ---- PV: lane owns dim d; vector-read w (float4) + kidx (uint4) ----
  const int b = bh >> 4, h = bh & 15;
#pragma unroll
  for (int qq = 0; qq < 4; ++qq) {
    const int qi2 = qg + qq;
    const float4 w0 = *(const float4*)&scr[qi2][0];
    const float4 w1 = *(const float4*)&scr[qi2][4];
    const float4 w2 = *(const float4*)&scr[qi2][8];
    const float4 w3 = *(const float4*)&scr[qi2][12];
    const uint4  kA = *(const uint4*)&kfin[qi2][0];
    const uint4  kB = *(const uint4*)&kfin[qi2][8];
    float acc = 0.f;
    acc = fmaf(w0.x, vb[(size_t)(kA.x & 0xffff) * HD + lane], acc);
    acc = fmaf(w0.y, vb[(size_t)(kA.x >> 16)    * HD + lane], acc);
    acc = fmaf(w0.z, vb[(size_t)(kA.y & 0xffff) * HD + lane], acc);
    acc = fmaf(w0.w, vb[(size_t)(kA.y >> 16)    * HD + lane], acc);
    acc = fmaf(w1.x, vb[(size_t)(kA.z & 0xffff) * HD + lane], acc);
    acc = fmaf(w1.y, vb[(size_t)(kA.z >> 16)    * HD + lane], acc);
    acc = fmaf(w1.z, vb[(size_t)(kA.w & 0xffff) * HD + lane], acc);
    acc = fmaf(w1.w, vb[(size_t)(kA.w >> 16)    * HD + lane], acc);
    acc = fmaf(w2.x, vb[(size_t)(kB.x & 0xffff) * HD + lane], acc);
    acc = fmaf(w2.y, vb[(size_t)(kB.x >> 16)    * HD + lane], acc);
    acc = fmaf(w2.z, vb[(size_t)(kB.y & 0xffff) * HD + lane], acc);
    acc = fmaf(w2.w, vb[(size_t)(kB.y >> 16)    * HD + lane], acc);
    acc = fmaf(w3.x, vb[(size_t)(kB.z & 0xffff) * HD + lane], acc);
    acc = fmaf(w3.y, vb[(size_t)(kB.z >> 16)    * HD + lane], acc);
    acc = fmaf(w3.z, vb[(size_t)(kB.w & 0xffff) * HD + lane], acc);
    acc = fmaf(w3.w, vb[(size_t)(kB.w >> 16)    * HD + lane], acc);
    ctx[((size_t)b * SEQ + (s0 + qq)) * EMB + h * HD + lane] = acc;
  }
}

// ---------------------------------------------------------------------------
extern "C" void kernel_launch(void* const* d_in, const int* in_sizes, int n_in,
                              void* d_out, int out_size, void* d_ws, size_t ws_size,
                              hipStream_t stream) {
  const float* x  = (const float*)d_in[0];
  const float* Wq = (const float*)d_in[1];
  const float* bq = (const float*)d_in[2];
  const float* Wk = (const float*)d_in[3];
  const float* bk = (const float*)d_in[4];
  const float* Wv = (const float*)d_in[5];
  const float* bv = (const float*)d_in[6];
  const float* Wo = (const float*)d_in[7];
  const float* bo = (const float*)d_in[8];
  float* out = (float*)d_out;

  const size_t SZ = (size_t)BATCH * NHEAD * SEQ * HD;
  float* qw = (float*)d_ws;
  float* kw = qw + SZ;
  float* vw = kw + SZ;
  float* cw = vw + SZ;

  dim3 blk(256);
  gemm_eigen_qk<<<dim3(64, 16, 2), blk, 0, stream>>>(x, Wq, bq, Wk, bk, qw, kw);
  gemm_mfma<1><<<dim3(64, 16), blk, 0, stream>>>(x, Wv, bv, vw);
  prune_attn8<<<dim3(BATCH * NHEAD * (SEQ / 16)), blk, 0, stream>>>(qw, kw, vw, cw);
  gemm_mfma<0><<<dim3(64, 16), blk, 0, stream>>>(cw, Wo, bo, out);
}